// Round 2
// 1116.580 us; speedup vs baseline: 1.0791x; 1.0791x over previous
//
#include <hip/hip_runtime.h>

#define B_ 65536
#define SEQ_ 2
#define P_ 1009
#define D_ 256
#define H_ 4
#define DH_ 64
#define HID_ 1024

typedef unsigned short u16;
typedef __attribute__((ext_vector_type(8))) short short8;
typedef __attribute__((ext_vector_type(4))) float f32x4;

__device__ __forceinline__ u16 f2b(float f) {
  unsigned int u = __float_as_uint(f);
  u += 0x7fffu + ((u >> 16) & 1u);   // RNE
  return (u16)(u >> 16);
}

// ---------------- precompute Q/K/VO tables over (token, pos) ----------------
// Qtab/Ktab: [P][2][256] f32, VOtab: [P][2][4][256] f32
__global__ __launch_bounds__(256) void prep_tables(
    const float* __restrict__ tok_emb, const float* __restrict__ pos_emb,
    const float* __restrict__ W_Q, const float* __restrict__ W_K,
    const float* __restrict__ W_V, const float* __restrict__ W_O,
    const float* __restrict__ b_Q, const float* __restrict__ b_K,
    const float* __restrict__ b_V,
    float* __restrict__ Qtab, float* __restrict__ Ktab,
    float* __restrict__ VOtab) {
  __shared__ float sh[D_];
  __shared__ float sv[D_];
  int blk = blockIdx.x;            // t*2 + p
  int t = blk >> 1, p = blk & 1;
  int j = threadIdx.x;             // 0..255
  sh[j] = tok_emb[t * D_ + j] + pos_emb[p * D_ + j];
  __syncthreads();
  int h = j >> 6, e = j & 63;
  float qv = b_Q[j], kv = b_K[j], vv = b_V[j];
  const float* wq = W_Q + h * (D_ * DH_) + e;
  const float* wk = W_K + h * (D_ * DH_) + e;
  const float* wvp = W_V + h * (D_ * DH_) + e;
  for (int k = 0; k < D_; ++k) {
    float hv = sh[k];
    qv += hv * wq[k * DH_];
    kv += hv * wk[k * DH_];
    vv += hv * wvp[k * DH_];
  }
  Qtab[blk * D_ + j] = qv;
  Ktab[blk * D_ + j] = kv;
  sv[j] = vv;
  __syncthreads();
  int d = j;
  for (int h2 = 0; h2 < H_; ++h2) {
    float acc = 0.f;
    const float* wo = W_O + h2 * (DH_ * D_) + d;
    for (int e2 = 0; e2 < DH_; ++e2) acc += sv[h2 * DH_ + e2] * wo[e2 * D_];
    VOtab[((size_t)blk * H_ + h2) * D_ + d] = acc;
  }
}

// ---------------- repack weights to bf16 ------------------------------------
// fc1b / unb: swizzled rows for gemm_regA — element (n,k) stored at column
// ((k>>3) ^ (n&7))*8 + (k&7)  (16B-slot XOR), so a LINEAR global_load_lds
// deposit + XOR'd ds_read_b128 in the GEMM is bank-conflict-free (G21:
// source permutation == read permutation). fc2b stays linear (old gemm_bt).
__global__ __launch_bounds__(256) void prep_weights(
    const float* __restrict__ fc1_w, const float* __restrict__ fc2_w,
    const float* __restrict__ un_w,
    u16* __restrict__ fc1b, u16* __restrict__ fc2b, u16* __restrict__ unb) {
  int i = blockIdx.x * 256 + threadIdx.x;  // < 262144
  int n = i >> 8, k = i & 255;
  int ksw = (((k >> 3) ^ (n & 7)) << 3) | (k & 7);
  fc1b[n * 256 + ksw] = f2b(fc1_w[i]);
  fc2b[i] = f2b(fc2_w[i]);
  unb[n * 256 + ksw] = (n < P_) ? f2b(un_w[i]) : (u16)0;  // pad 1009 -> 1024
}

// ---------------- attention per b: tiny dots + weighted VO gather -----------
__global__ __launch_bounds__(256) void attn_kernel(
    const int* __restrict__ x, const float* __restrict__ Qtab,
    const float* __restrict__ Ktab, const float* __restrict__ VOtab,
    const float* __restrict__ b_O, u16* __restrict__ attn_out) {
  __shared__ float sQ[2][D_];
  __shared__ float sK[2][D_];
  __shared__ float ssc[16];
  __shared__ float spat[16];
  int b = blockIdx.x;
  int t = threadIdx.x;
  int x0 = x[2 * b + 0];
  int x1 = x[2 * b + 1];
  sQ[0][t] = Qtab[(x0 * 2 + 0) * D_ + t];
  sQ[1][t] = Qtab[(x1 * 2 + 1) * D_ + t];
  sK[0][t] = Ktab[(x0 * 2 + 0) * D_ + t];
  sK[1][t] = Ktab[(x1 * 2 + 1) * D_ + t];
  __syncthreads();
  if (t < 16) {                       // t = h*4 + i*2 + j
    int h = t >> 2, i = (t >> 1) & 1, jj = t & 1;
    const float* q = &sQ[i][h * DH_];
    const float* k = &sK[jj][h * DH_];
    float s = 0.f;
    for (int e = 0; e < DH_; ++e) s += q[e] * k[e];
    ssc[t] = s * 0.125f;              // / sqrt(64)
  }
  __syncthreads();
  if (t < 8) {                        // t = h*2 + i
    int h = t >> 1, i = t & 1;
    float s0 = ssc[h * 4 + i * 2 + 0];
    float s1 = ssc[h * 4 + i * 2 + 1];
    float m = fmaxf(s0, s1);
    float e0 = __expf(s0 - m), e1 = __expf(s1 - m);
    float inv = 1.f / (e0 + e1);
    spat[h * 4 + i * 2 + 0] = 0.5f + 0.5f * e0 * inv;  // blended softmax
    spat[h * 4 + i * 2 + 1] = 0.5f + 0.5f * e1 * inv;
  }
  __syncthreads();
  int d = t;
  float bo = b_O[d];
  float o0 = bo, o1 = bo;
  for (int jj = 0; jj < 2; ++jj) {
    int xj = jj ? x1 : x0;
    const float* vo = VOtab + (size_t)(xj * 2 + jj) * (H_ * D_) + d;
    for (int h = 0; h < H_; ++h) {
      float v = vo[h * D_];
      o0 += spat[h * 4 + 0 + jj] * v;   // i=0
      o1 += spat[h * 4 + 2 + jj] * v;   // i=1
    }
  }
  attn_out[(size_t)(2 * b + 0) * D_ + d] = f2b(o0);
  attn_out[(size_t)(2 * b + 1) * D_ + d] = f2b(o1);
}

// ---------------- MFMA GEMM (K-loop structure, kept for fc2: K=1024) --------
template <bool RELU, bool STORE_F32>
__global__ __launch_bounds__(256) void gemm_bt(
    const u16* __restrict__ A, const u16* __restrict__ Bt,
    const float* __restrict__ bias, void* __restrict__ Cout,
    int K, int ldc, int Neff) {
  __shared__ u16 lds_a[128 * 64];
  __shared__ u16 lds_b[128 * 64];
  int tid = threadIdx.x;
  int lane = tid & 63;
  int wv = tid >> 6;
  int wr = wv >> 1, wc = wv & 1;
  int m0 = blockIdx.x * 128;
  int n0 = blockIdx.y * 128;
  f32x4 acc[4][4] = {};
  int lr = lane >> 3;
  int lc = (lane & 7) * 8;
  int q = lane >> 4;
  int mrow = lane & 15;

  for (int k0 = 0; k0 < K; k0 += 64) {
#pragma unroll
    for (int i = 0; i < 4; ++i) {
      int row = i * 32 + wv * 8 + lr;
      const u16* g = A + (size_t)(m0 + row) * K + k0 + lc;
      __builtin_amdgcn_global_load_lds(
          (const __attribute__((address_space(1))) void*)g,
          (__attribute__((address_space(3))) void*)&lds_a[row * 64 + lc], 16, 0, 0);
    }
#pragma unroll
    for (int i = 0; i < 4; ++i) {
      int row = i * 32 + wv * 8 + lr;
      const u16* g = Bt + (size_t)(n0 + row) * K + k0 + lc;
      __builtin_amdgcn_global_load_lds(
          (const __attribute__((address_space(1))) void*)g,
          (__attribute__((address_space(3))) void*)&lds_b[row * 64 + lc], 16, 0, 0);
    }
    __syncthreads();
#pragma unroll
    for (int kk = 0; kk < 64; kk += 32) {
      short8 af[4], bfr[4];
#pragma unroll
      for (int tt = 0; tt < 4; ++tt)
        af[tt] = *(const short8*)&lds_a[(wr * 64 + tt * 16 + mrow) * 64 + kk + q * 8];
#pragma unroll
      for (int uu = 0; uu < 4; ++uu)
        bfr[uu] = *(const short8*)&lds_b[(wc * 64 + uu * 16 + mrow) * 64 + kk + q * 8];
#pragma unroll
      for (int tt = 0; tt < 4; ++tt)
#pragma unroll
        for (int uu = 0; uu < 4; ++uu)
          acc[tt][uu] = __builtin_amdgcn_mfma_f32_16x16x32_bf16(
              af[tt], bfr[uu], acc[tt][uu], 0, 0, 0);
    }
    __syncthreads();
  }

  int cn = lane & 15;
#pragma unroll
  for (int tt = 0; tt < 4; ++tt) {
    int gm = m0 + wr * 64 + tt * 16 + q * 4;
#pragma unroll
    for (int uu = 0; uu < 4; ++uu) {
      int gn = n0 + wc * 64 + uu * 16 + cn;
      if (gn < Neff) {
        float bv = bias[gn];
#pragma unroll
        for (int r = 0; r < 4; ++r) {
          float v = acc[tt][uu][r] + bv;
          if (RELU) v = fmaxf(v, 0.f);
          if (STORE_F32)
            ((float*)Cout)[(size_t)(gm + r) * ldc + gn] = v;
          else
            ((u16*)Cout)[(size_t)(gm + r) * ldc + gn] = f2b(v);
        }
      }
    }
  }
}

// ---------------- K=256 GEMM: A-fragments in registers, B streamed ----------
// C[M x N] = A[M x 256] @ Bsw[N x 256]^T + bias, Bsw pre-swizzled (see
// prep_weights). Block = 128 rows of A, 4 waves in 2(M) x 2(N).
// A-frags loaded once (af[4][8], 128 VGPR, 64B-coalesced global reads).
// N-loop (Ntiles x 64 cols, must be even): double-buffered 32KB B tiles,
// prefetch issued BEFORE the MFMA phase, one __syncthreads per tile.
// ds_read_b128 of B applies the slot-XOR -> uniform bank spread (free).
template <bool RELU, bool STORE_F32>
__global__ __launch_bounds__(256, 2) void gemm_regA(
    const u16* __restrict__ A, const u16* __restrict__ Bsw,
    const float* __restrict__ bias, void* __restrict__ Cout,
    int Ntiles, int ldc, int Neff) {
  __shared__ u16 lb[2][64 * 256];     // 2 x 32KB
  int tid = threadIdx.x;
  int lane = tid & 63;
  int wv = tid >> 6;
  int wm = wv >> 1, wn = wv & 1;
  int q = lane >> 4, mrow = lane & 15;
  size_t m0 = (size_t)blockIdx.x * 128;

  // A fragments: rows m0 + wm*64 + tt*16 + mrow, k = ks*32 + q*8 .. +8
  short8 af[4][8];
#pragma unroll
  for (int tt = 0; tt < 4; ++tt)
#pragma unroll
    for (int ks = 0; ks < 8; ++ks)
      af[tt][ks] = *(const short8*)(A + (m0 + wm * 64 + tt * 16 + mrow) * 256 +
                                    ks * 32 + q * 8);

  auto stageB = [&](int bi, int nt) {
#pragma unroll
    for (int r2 = 0; r2 < 8; ++r2) {
      int off = r2 * 2048 + tid * 8;  // elements; lane-linear 16B chunks
      __builtin_amdgcn_global_load_lds(
          (const __attribute__((address_space(1))) void*)(Bsw + (size_t)nt * (64 * 256) + off),
          (__attribute__((address_space(3))) void*)(&lb[bi][off]), 16, 0, 0);
    }
  };

  int rb0 = (wn * 32 + mrow) * 256;   // uu=0 B-row base (elements)
  int rb1 = rb0 + 16 * 256;           // uu=1
  int s = mrow & 7;                   // swizzle key (== global n & 7)

  auto tile = [&](int bi, int nt) {
    const u16* bb = &lb[bi][0];
    f32x4 acc[4][2] = {};
#pragma unroll
    for (int ks = 0; ks < 8; ++ks) {
      int e = ((ks * 4 + q) ^ s) << 3;
      short8 b0 = *(const short8*)(bb + rb0 + e);
      short8 b1 = *(const short8*)(bb + rb1 + e);
#pragma unroll
      for (int tt = 0; tt < 4; ++tt) {
        acc[tt][0] = __builtin_amdgcn_mfma_f32_16x16x32_bf16(af[tt][ks], b0, acc[tt][0], 0, 0, 0);
        acc[tt][1] = __builtin_amdgcn_mfma_f32_16x16x32_bf16(af[tt][ks], b1, acc[tt][1], 0, 0, 0);
      }
    }
    int n0 = nt * 64 + wn * 32;
#pragma unroll
    for (int uu = 0; uu < 2; ++uu) {
      int gn = n0 + uu * 16 + mrow;
      if (gn < Neff) {
        float bv = bias[gn];
#pragma unroll
        for (int tt = 0; tt < 4; ++tt) {
          size_t gm = m0 + wm * 64 + tt * 16 + q * 4;
#pragma unroll
          for (int r = 0; r < 4; ++r) {
            float v = acc[tt][uu][r] + bv;
            if (RELU) v = fmaxf(v, 0.f);
            if (STORE_F32)
              ((float*)Cout)[(gm + r) * ldc + gn] = v;
            else
              ((u16*)Cout)[(gm + r) * ldc + gn] = f2b(v);
          }
        }
      }
    }
  };

  stageB(0, 0);
  __syncthreads();
  for (int nt = 0; nt < Ntiles; nt += 2) {   // ping-pong, static buffer ids
    if (nt + 1 < Ntiles) stageB(1, nt + 1);
    tile(0, nt);
    __syncthreads();
    if (nt + 2 < Ntiles) stageB(0, nt + 2);
    tile(1, nt + 1);
    __syncthreads();
  }
}

extern "C" void kernel_launch(void* const* d_in, const int* in_sizes, int n_in,
                              void* d_out, int out_size, void* d_ws, size_t ws_size,
                              hipStream_t stream) {
  const int* x = (const int*)d_in[0];
  const float* tok_emb = (const float*)d_in[1];
  const float* pos_emb = (const float*)d_in[2];
  const float* W_Q = (const float*)d_in[3];
  const float* W_K = (const float*)d_in[4];
  const float* W_V = (const float*)d_in[5];
  const float* W_O = (const float*)d_in[6];
  const float* b_Q = (const float*)d_in[7];
  const float* b_K = (const float*)d_in[8];
  const float* b_V = (const float*)d_in[9];
  const float* b_O = (const float*)d_in[10];
  const float* fc1_w = (const float*)d_in[11];
  const float* fc1_b = (const float*)d_in[12];
  const float* fc2_w = (const float*)d_in[13];
  const float* fc2_b = (const float*)d_in[14];
  const float* un_w = (const float*)d_in[15];
  const float* un_b = (const float*)d_in[16];

  char* ws = (char*)d_ws;
  size_t off = 0;
  auto alloc = [&](size_t bytes) {
    void* p = ws + off;
    off = (off + bytes + 255) & ~(size_t)255;
    return p;
  };
  float* Qtab = (float*)alloc((size_t)P_ * 2 * D_ * 4);
  float* Ktab = (float*)alloc((size_t)P_ * 2 * D_ * 4);
  float* VOtab = (float*)alloc((size_t)P_ * 2 * H_ * D_ * 4);
  u16* fc1b = (u16*)alloc((size_t)HID_ * D_ * 2);
  u16* fc2b = (u16*)alloc((size_t)D_ * HID_ * 2);
  u16* unb = (u16*)alloc((size_t)1024 * D_ * 2);
  u16* attn = (u16*)alloc((size_t)B_ * 2 * D_ * 2);
  u16* resid = (u16*)alloc((size_t)B_ * 2 * D_ * 2);
  // hid [131072 x 1024] bf16 = 268 MB lives in d_out (529 MB), dead before
  // the unembed GEMM overwrites d_out with f32 logits.
  u16* hid = (u16*)d_out;

  prep_tables<<<P_ * 2, 256, 0, stream>>>(tok_emb, pos_emb, W_Q, W_K, W_V, W_O,
                                          b_Q, b_K, b_V, Qtab, Ktab, VOtab);
  prep_weights<<<1024, 256, 0, stream>>>(fc1_w, fc2_w, un_w, fc1b, fc2b, unb);
  attn_kernel<<<B_, 256, 0, stream>>>(x, Qtab, Ktab, VOtab, b_O, attn);
  // fc1 + relu: [131072 x 256] @ [1024 x 256]^T -> hid bf16   (regA, K=256)
  gemm_regA<true, false><<<1024, 256, 0, stream>>>(attn, fc1b, fc1_b, hid, 16, HID_, HID_);
  // fc2: [131072 x 1024] @ [256 x 1024]^T -> resid bf16       (K=1024, old path)
  gemm_bt<false, false><<<dim3(1024, 2), 256, 0, stream>>>(hid, fc2b, fc2_b, resid, HID_, D_, D_);
  // unembed: [131072 x 256] @ [1024(pad) x 256]^T -> logits f32 (regA, K=256)
  gemm_regA<false, true><<<1024, 256, 0, stream>>>(resid, unb, un_b, d_out, 16, P_, P_);
}